// Round 8
// baseline (132.833 us; speedup 1.0000x reference)
//
#include <hip/hip_runtime.h>

// RotMap: Y[n,a,b,i,f] = sum_c w[a,c,i] * x[n,c,b,i,f]
// N=256, D=3, NUM=342, FRAME=100
// x layout (row-major): [N][c:3][b:3][i:342][f:100]
// w layout:             [a:3][c:3][i:342]
// y layout:             [N][a:3][b:3][i:342][f:100]

typedef float f4 __attribute__((ext_vector_type(4)));

#define RN     256
#define RD     3
#define RNUM   342
#define RFRAME 100
#define RM     (RNUM * RFRAME)        // 34200 fused (i,f)
#define RM4    (RM / 4)               // 8550 float4 groups (FRAME%4==0 -> uniform i per group)
#define RTOT4  (RN * RD * RM4)        // 6,566,400 float4 work items
#define RCSTR4 (RD * RM / 4)          // 25650: c (and a) stride in float4 units
#define RWSRC  (RD * RD * RNUM)       // 3078 source w floats

#define RGRID   2048
#define RSTRIDE (RGRID * 256)         // 524288 threads
// RTOT4 = 12*RSTRIDE + 274944 -> every thread owns 12 items; first 274944 own a 13th.

// Write-path split: evidence R2-R6 shows nt stores cap at ~2.65 TB/s and were
// the binding limit (write time == dur in 4 configs); R7 shows all-plain
// stores thrash x out of L3. Split: first 96 MiB of y goes via plain stores
// (L3-resident window, re-dirtied in place across replays -> ~no writebacks),
// rest via nt (bypass). 96 MiB + ~150 MB retained x < 256 MiB L3.
#define YTH4 6291456u                 // 96 MiB / 16 B, in f4 units

__device__ __forceinline__ void decomp(unsigned t, unsigned& base4, unsigned& i) {
    const unsigned m4 = t % RM4;
    const unsigned nb = t / RM4;      // n*3 + b
    i = m4 / 25;                      // rotation index (uniform within the float4)
    const unsigned n = nb / RD;
    const unsigned b = nb - n * RD;
    base4 = (n * (RD * RD) + b) * RM4 + m4;
}

// wt layout in LDS: [i][a] -> f4 {w[a][0][i], w[a][1][i], w[a][2][i], pad}
__device__ __forceinline__ void compute_store(const f4* __restrict__ wt, unsigned i,
                                              unsigned b4, f4 x0, f4 x1, f4 x2,
                                              f4* __restrict__ y) {
    const f4* wrow = wt + i * RD;
    f4* yp = y + b4;
#pragma unroll
    for (int a = 0; a < RD; ++a) {
        const f4 wa = wrow[a];        // one ds_read_b128
        f4 o;
#pragma unroll
        for (int j = 0; j < 4; ++j)
            o[j] = fmaf(wa.x, x0[j], fmaf(wa.y, x1[j], wa.z * x2[j]));
        if (b4 + (unsigned)(a * RCSTR4) < YTH4)   // nearly wave-uniform
            yp[a * RCSTR4] = o;                   // L3 window: plain store
        else
            __builtin_nontemporal_store(o, yp + a * RCSTR4);
    }
}

#define LOADQ(R, B, I, tq)                                                   \
    do {                                                                     \
        decomp((tq),               B[0], I[0]);                              \
        decomp((tq) + RSTRIDE,     B[1], I[1]);                              \
        decomp((tq) + 2 * RSTRIDE, B[2], I[2]);                              \
        decomp((tq) + 3 * RSTRIDE, B[3], I[3]);                              \
        _Pragma("unroll")                                                    \
        for (int q = 0; q < 4; ++q) {                                        \
            const f4* xp = x + B[q];                                         \
            R##0[q] = xp[0];                                                 \
            R##1[q] = xp[RCSTR4];                                            \
            R##2[q] = xp[2 * RCSTR4];                                        \
        }                                                                    \
    } while (0)

#define COMPQ(R, B, I)                                                       \
    do {                                                                     \
        _Pragma("unroll")                                                    \
        for (int q = 0; q < 4; ++q)                                          \
            compute_store(wt, I[q], B[q], R##0[q], R##1[q], R##2[q], y);     \
    } while (0)

__global__ __launch_bounds__(256, 8) void
rotmap_kernel(const f4* __restrict__ x, const float* __restrict__ w,
              f4* __restrict__ y) {
    __shared__ f4 wt[RNUM * RD];      // 342*3 f4 = 16.4 KB, [i][a]
    for (int idx = threadIdx.x; idx < RWSRC; idx += 256) {
        const int a = idx / (RD * RNUM);
        const int rem = idx - a * RD * RNUM;
        const int c = rem / RNUM;
        const int i = rem - c * RNUM;
        ((float*)&wt[i * RD + a])[c] = w[idx];
    }
    __syncthreads();

    const unsigned t = blockIdx.x * 256 + threadIdx.x;

    f4 A0[4], A1[4], A2[4], B0[4], B1[4], B2[4];
    unsigned bA[4], iA[4], bB[4], iB[4];

    LOADQ(A, bA, iA, t);                       // quad 0 (items 0-3)
    LOADQ(B, bB, iB, t + 4 * RSTRIDE);         // quad 1 (items 4-7)
    COMPQ(A, bA, iA);
    LOADQ(A, bA, iA, t + 8 * RSTRIDE);         // quad 2 (items 8-11)
    COMPQ(B, bB, iB);
    COMPQ(A, bA, iA);

    // 13th item for the first 274,944 threads.
    const unsigned t13 = t + 12 * RSTRIDE;
    if (t13 < RTOT4) {
        unsigned b4, i;
        decomp(t13, b4, i);
        const f4* xp = x + b4;
        compute_store(wt, i, b4, xp[0], xp[RCSTR4], xp[2 * RCSTR4], y);
    }
}

extern "C" void kernel_launch(void* const* d_in, const int* in_sizes, int n_in,
                              void* d_out, int out_size, void* d_ws, size_t ws_size,
                              hipStream_t stream) {
    const f4* x = (const f4*)d_in[0];
    const float* w = (const float*)d_in[1];
    f4* y = (f4*)d_out;

    // Grid MUST stay RGRID: the kernel assumes 12-13 items/thread at RSTRIDE.
    rotmap_kernel<<<RGRID, 256, 0, stream>>>(x, w, y);
}

// Round 9
// 117.402 us; speedup vs baseline: 1.1314x; 1.1314x over previous
//
#include <hip/hip_runtime.h>

// RotMap: Y[n,a,b,i,f] = sum_c w[a,c,i] * x[n,c,b,i,f]
// N=256, D=3, NUM=342, FRAME=100
// x layout (row-major): [N][c:3][b:3][i:342][f:100]
// w layout:             [a:3][c:3][i:342]
// y layout:             [N][a:3][b:3][i:342][f:100]
//
// Final config (best measured, R6 = 116.6 us):
//   - plain (cached) loads of x: L3 retains ~50% of x across graph replays
//     (FETCH 157 MB vs 315 MB), nt-load hints proven null (R6).
//   - nontemporal stores of y: bypass L2/L3; plain stores evict x and
//     regress 14% (R7/R8).
//   - (256,8): 32 waves/CU; static 3-quad pipeline (neutral but harmless).
//   - measured ceiling: 630 MB app bytes / 116.6 us = 5.4 TB/s = 86% of the
//     m13 float4-copy ceiling; write stream binds at ~2.65 TB/s.

typedef float f4 __attribute__((ext_vector_type(4)));

#define RN     256
#define RD     3
#define RNUM   342
#define RFRAME 100
#define RM     (RNUM * RFRAME)        // 34200 fused (i,f)
#define RM4    (RM / 4)               // 8550 float4 groups (FRAME%4==0 -> uniform i per group)
#define RTOT4  (RN * RD * RM4)        // 6,566,400 float4 work items
#define RCSTR4 (RD * RM / 4)          // 25650: c (and a) stride in float4 units
#define RWSRC  (RD * RD * RNUM)       // 3078 source w floats

#define RGRID   2048
#define RSTRIDE (RGRID * 256)         // 524288 threads
// RTOT4 = 12*RSTRIDE + 274944 -> every thread owns 12 items; first 274944 own a 13th.

__device__ __forceinline__ void decomp(unsigned t, unsigned& base4, unsigned& i) {
    const unsigned m4 = t % RM4;
    const unsigned nb = t / RM4;      // n*3 + b
    i = m4 / 25;                      // rotation index (uniform within the float4)
    const unsigned n = nb / RD;
    const unsigned b = nb - n * RD;
    base4 = (n * (RD * RD) + b) * RM4 + m4;
}

// wt layout in LDS: [i][a] -> f4 {w[a][0][i], w[a][1][i], w[a][2][i], pad}
__device__ __forceinline__ void compute_store(const f4* __restrict__ wt, unsigned i,
                                              f4 x0, f4 x1, f4 x2,
                                              f4* __restrict__ yp) {
    const f4* wrow = wt + i * RD;
#pragma unroll
    for (int a = 0; a < RD; ++a) {
        const f4 wa = wrow[a];        // one ds_read_b128
        f4 o;
#pragma unroll
        for (int j = 0; j < 4; ++j)
            o[j] = fmaf(wa.x, x0[j], fmaf(wa.y, x1[j], wa.z * x2[j]));
        __builtin_nontemporal_store(o, yp + a * RCSTR4);
    }
}

#define LOADQ(R, B, I, tq)                                                   \
    do {                                                                     \
        decomp((tq),               B[0], I[0]);                              \
        decomp((tq) + RSTRIDE,     B[1], I[1]);                              \
        decomp((tq) + 2 * RSTRIDE, B[2], I[2]);                              \
        decomp((tq) + 3 * RSTRIDE, B[3], I[3]);                              \
        _Pragma("unroll")                                                    \
        for (int q = 0; q < 4; ++q) {                                        \
            const f4* xp = x + B[q];                                         \
            R##0[q] = xp[0];                                                 \
            R##1[q] = xp[RCSTR4];                                            \
            R##2[q] = xp[2 * RCSTR4];                                        \
        }                                                                    \
    } while (0)

#define COMPQ(R, B, I)                                                       \
    do {                                                                     \
        _Pragma("unroll")                                                    \
        for (int q = 0; q < 4; ++q)                                          \
            compute_store(wt, I[q], R##0[q], R##1[q], R##2[q], y + B[q]);    \
    } while (0)

__global__ __launch_bounds__(256, 8) void
rotmap_kernel(const f4* __restrict__ x, const float* __restrict__ w,
              f4* __restrict__ y) {
    __shared__ f4 wt[RNUM * RD];      // 342*3 f4 = 16.4 KB, [i][a]
    for (int idx = threadIdx.x; idx < RWSRC; idx += 256) {
        const int a = idx / (RD * RNUM);
        const int rem = idx - a * RD * RNUM;
        const int c = rem / RNUM;
        const int i = rem - c * RNUM;
        ((float*)&wt[i * RD + a])[c] = w[idx];
    }
    __syncthreads();

    const unsigned t = blockIdx.x * 256 + threadIdx.x;

    f4 A0[4], A1[4], A2[4], B0[4], B1[4], B2[4];
    unsigned bA[4], iA[4], bB[4], iB[4];

    LOADQ(A, bA, iA, t);                       // quad 0 (items 0-3)
    LOADQ(B, bB, iB, t + 4 * RSTRIDE);         // quad 1 (items 4-7)
    COMPQ(A, bA, iA);
    LOADQ(A, bA, iA, t + 8 * RSTRIDE);         // quad 2 (items 8-11)
    COMPQ(B, bB, iB);
    COMPQ(A, bA, iA);

    // 13th item for the first 274,944 threads.
    const unsigned t13 = t + 12 * RSTRIDE;
    if (t13 < RTOT4) {
        unsigned b4, i;
        decomp(t13, b4, i);
        const f4* xp = x + b4;
        compute_store(wt, i, xp[0], xp[RCSTR4], xp[2 * RCSTR4], y + b4);
    }
}

extern "C" void kernel_launch(void* const* d_in, const int* in_sizes, int n_in,
                              void* d_out, int out_size, void* d_ws, size_t ws_size,
                              hipStream_t stream) {
    const f4* x = (const f4*)d_in[0];
    const float* w = (const float*)d_in[1];
    f4* y = (f4*)d_out;

    // Grid MUST stay RGRID: the kernel assumes 12-13 items/thread at RSTRIDE.
    rotmap_kernel<<<RGRID, 256, 0, stream>>>(x, w, y);
}